// Round 1
// 653.915 us; speedup vs baseline: 1.1839x; 1.1839x over previous
//
#include <hip/hip_runtime.h>
#include <stdint.h>

typedef unsigned short bf16_t;

constexpr int kNN   = 100000;
constexpr int kNE   = 1600000;
constexpr int kFEAT = 256;
constexpr int kHID  = 128;
constexpr int kOUT  = 64;
constexpr int kNB   = 10000;
constexpr float kEPS = 1e-5f;

typedef __attribute__((ext_vector_type(8))) short short8v;
typedef __attribute__((ext_vector_type(4))) float f32x4;

__device__ __forceinline__ float bf2f(bf16_t u) {
    union { uint32_t i; float f; } v; v.i = ((uint32_t)u) << 16; return v.f;
}
__device__ __forceinline__ bf16_t f2bf(float f) {
    uint32_t u = __float_as_uint(f);
    uint32_t r = (u + 0x7FFFu + ((u >> 16) & 1u)) >> 16;
    return (bf16_t)r;
}
__device__ __forceinline__ float lo16(uint32_t u) {
    union { uint32_t i; float f; } v; v.i = u << 16; return v.f;
}
__device__ __forceinline__ float hi16(uint32_t u) {
    union { uint32_t i; float f; } v; v.i = u & 0xFFFF0000u; return v.f;
}

// flags[0]: 1 if float tensors are bf16, 0 if fp32.  flags[1]: 1 if edge_index int64.
__global__ void k_probe(const uint32_t* __restrict__ feat, const uint32_t* __restrict__ ei,
                        int* __restrict__ flags) {
    if (blockIdx.x == 0 && threadIdx.x == 0) {
        int good = 0;
        for (int j = 0; j < 256; j++) {
            uint32_t u = feat[j];
            uint32_t e = (u >> 7) & 0xFFu;
            if (e >= 100u && e <= 132u) good++;
        }
        flags[0] = (good > 128) ? 1 : 0;
        int zeros = 0;
        for (int j = 0; j < 128; j++) {
            if (ei[2 * j + 1] == 0u) zeros++;
        }
        flags[1] = (zeros > 64) ? 1 : 0;
    }
}

__global__ void k_setup(unsigned int* __restrict__ deg, float* __restrict__ stats,
                        unsigned int* __restrict__ gtotal) {
    int i = blockIdx.x * 256 + threadIdx.x;
    if (i < kNN) deg[i] = 1u;   // self loop
    if (i < 384) stats[i] = 0.f;
    if (i == 0) gtotal[0] = 0u;
}

__global__ void k_deg(const int* __restrict__ ei, const int* __restrict__ flags,
                      unsigned int* __restrict__ deg) {
    int e = blockIdx.x * 256 + threadIdx.x;
    if (e >= kNE) return;
    int d = flags[1] ? ei[2 * (kNE + e)] : ei[kNE + e];
    atomicAdd(&deg[d], 1u);
}

__global__ void k_dinv(const unsigned int* __restrict__ deg, float* __restrict__ dinv) {
    int i = blockIdx.x * 256 + threadIdx.x;
    if (i < kNN) dinv[i] = rsqrtf((float)deg[i]);
}

// per-block scan + one atomic -> CSR slice base per node (order irrelevant)
__global__ void k_assign(const unsigned int* __restrict__ deg, unsigned int* __restrict__ cursor,
                         unsigned int* __restrict__ gtotal) {
    __shared__ unsigned int ss[256];
    __shared__ unsigned int sbase;
    int t = threadIdx.x;
    int i = blockIdx.x * 256 + t;
    unsigned int v = (i < kNN) ? (deg[i] - 1u) : 0u;
    ss[t] = v;
    __syncthreads();
    for (int off = 1; off < 256; off <<= 1) {
        unsigned int x = (t >= off) ? ss[t - off] : 0u;
        __syncthreads();
        ss[t] += x;
        __syncthreads();
    }
    if (t == 255) sbase = atomicAdd(gtotal, ss[255]);
    __syncthreads();
    if (i < kNN) cursor[i] = sbase + ss[t] - v;
}

__global__ void k_bucket(const int* __restrict__ ei, const int* __restrict__ flags,
                         unsigned int* __restrict__ cursor, int* __restrict__ sorted) {
    int e = blockIdx.x * 256 + threadIdx.x;
    if (e >= kNE) return;
    int s, d;
    if (flags[1]) { s = ei[2 * e]; d = ei[2 * (kNE + e)]; }
    else          { s = ei[e];     d = ei[kNE + e]; }
    unsigned int p = atomicAdd(&cursor[d], 1u);
    sorted[p] = s;
}

// Pre-swizzle W1 [256][128] into MFMA B-fragment order: Wz[(t*8+j)*64+l][i]
// = W[t*32 + 8*(l>>4) + i][j*16 + (l&15)]  (t: k-step 0..7, j: n-frag 0..7)
__global__ void k_prepw1(const void* __restrict__ W, const int* __restrict__ flags,
                         bf16_t* __restrict__ Wz) {
    int idx = blockIdx.x * 256 + threadIdx.x;
    if (idx >= 8 * 8 * 64) return;
    int l = idx & 63;
    int j = (idx >> 6) & 7;
    int t = idx >> 9;
    int col = j * 16 + (l & 15);
    int kb = t * 32 + (l >> 4) * 8;
    bf16_t o[8];
    if (flags[0]) {
        const bf16_t* Wb = (const bf16_t*)W;
        #pragma unroll
        for (int i = 0; i < 8; i++) o[i] = Wb[(size_t)(kb + i) * kHID + col];
    } else {
        const float* Wf = (const float*)W;
        #pragma unroll
        for (int i = 0; i < 8; i++) o[i] = f2bf(Wf[(size_t)(kb + i) * kHID + col]);
    }
    uint4 w;
    w.x = (uint32_t)o[0] | ((uint32_t)o[1] << 16);
    w.y = (uint32_t)o[2] | ((uint32_t)o[3] << 16);
    w.z = (uint32_t)o[4] | ((uint32_t)o[5] << 16);
    w.w = (uint32_t)o[6] | ((uint32_t)o[7] << 16);
    *(uint4*)(Wz + (size_t)idx * 8) = w;
}

// Same for W2 [128][64]: t 0..3, j 0..3
__global__ void k_prepw2(const void* __restrict__ W, const int* __restrict__ flags,
                         bf16_t* __restrict__ Wz) {
    int idx = blockIdx.x * 256 + threadIdx.x;
    if (idx >= 4 * 4 * 64) return;
    int l = idx & 63;
    int j = (idx >> 6) & 3;
    int t = idx >> 8;
    int col = j * 16 + (l & 15);
    int kb = t * 32 + (l >> 4) * 8;
    bf16_t o[8];
    if (flags[0]) {
        const bf16_t* Wb = (const bf16_t*)W;
        #pragma unroll
        for (int i = 0; i < 8; i++) o[i] = Wb[(size_t)(kb + i) * kOUT + col];
    } else {
        const float* Wf = (const float*)W;
        #pragma unroll
        for (int i = 0; i < 8; i++) o[i] = f2bf(Wf[(size_t)(kb + i) * kOUT + col]);
    }
    uint4 w;
    w.x = (uint32_t)o[0] | ((uint32_t)o[1] << 16);
    w.y = (uint32_t)o[2] | ((uint32_t)o[3] << 16);
    w.z = (uint32_t)o[4] | ((uint32_t)o[5] << 16);
    w.w = (uint32_t)o[6] | ((uint32_t)o[7] << 16);
    *(uint4*)(Wz + (size_t)idx * 8) = w;
}

// H[n,c] = dinv[n] * sum_k A[n,k]*W1[k,c]  via mfma_f32_16x16x32_bf16.
// Block = 128 rows, 4 waves; each wave owns 32 rows (2 m-frags) x 128 cols (8 n-frags).
// B fragments come straight from pre-swizzled Wz (L2-hot, 16B/lane) -> no LDS, no barriers.
__global__ void k_gemm1(const void* __restrict__ A, const bf16_t* __restrict__ Wz,
                        const float* __restrict__ dinv, bf16_t* __restrict__ H,
                        const int* __restrict__ flags) {
    int isbf = flags[0];
    int wv = threadIdx.x >> 6;
    int l  = threadIdx.x & 63;
    int kgrp = l >> 4;
    int rbase = blockIdx.x * 128 + wv * 32;
    int arow0 = rbase + (l & 15);
    int arow1 = arow0 + 16;
    const bf16_t* Ab = (const bf16_t*)A;
    const float*  Af = (const float*)A;
    const short8v* Wv = (const short8v*)Wz;

    f32x4 acc[2][8];
    #pragma unroll
    for (int m = 0; m < 2; m++)
        #pragma unroll
        for (int j = 0; j < 8; j++)
            acc[m][j] = (f32x4){0.f, 0.f, 0.f, 0.f};

    #pragma unroll
    for (int t = 0; t < 8; t++) {
        int kbase = t * 32 + kgrp * 8;
        short8v a0, a1;
        #pragma unroll
        for (int i = 0; i < 8; i++) { a0[i] = 0; a1[i] = 0; }
        if (arow0 < kNN) {
            if (isbf) {
                a0 = *(const short8v*)(Ab + (size_t)arow0 * kFEAT + kbase);
            } else {
                const float* p = Af + (size_t)arow0 * kFEAT + kbase;
                #pragma unroll
                for (int i = 0; i < 8; i++) a0[i] = (short)f2bf(p[i]);
            }
        }
        if (arow1 < kNN) {
            if (isbf) {
                a1 = *(const short8v*)(Ab + (size_t)arow1 * kFEAT + kbase);
            } else {
                const float* p = Af + (size_t)arow1 * kFEAT + kbase;
                #pragma unroll
                for (int i = 0; i < 8; i++) a1[i] = (short)f2bf(p[i]);
            }
        }
        #pragma unroll
        for (int j = 0; j < 8; j++) {
            short8v b = Wv[(t * 8 + j) * 64 + l];
            acc[0][j] = __builtin_amdgcn_mfma_f32_16x16x32_bf16(a0, b, acc[0][j], 0, 0, 0);
            acc[1][j] = __builtin_amdgcn_mfma_f32_16x16x32_bf16(a1, b, acc[1][j], 0, 0, 0);
        }
    }

    // D layout: col = l&15, row = (l>>4)*4 + r
    #pragma unroll
    for (int m = 0; m < 2; m++) {
        #pragma unroll
        for (int r = 0; r < 4; r++) {
            int orow = rbase + m * 16 + kgrp * 4 + r;
            if (orow < kNN) {
                float dn = dinv[orow];
                bf16_t* hp = H + (size_t)orow * kHID + (l & 15);
                #pragma unroll
                for (int j = 0; j < 8; j++) hp[j * 16] = f2bf(acc[m][j][r] * dn);
            }
        }
    }
}

// A1[n,c] = dinv[n]*(sum_edges Hs[s,c] + Hs[n,c]) + b1[c]; 4 nodes/block, 2ch/lane, unroll 4
__global__ void k_agg1(const bf16_t* __restrict__ H, const int* __restrict__ sorted,
                       const unsigned int* __restrict__ cursor, const unsigned int* __restrict__ deg,
                       const float* __restrict__ dinv, const void* __restrict__ bias,
                       const int* __restrict__ flags, float* __restrict__ Out) {
    int t = threadIdx.x;
    int local = t >> 6;
    int lane = t & 63;
    int c0 = lane * 2;
    int n = blockIdx.x * 4 + local;
    if (n >= kNN) return;
    const uint32_t* Hrow = (const uint32_t*)H;   // 2 bf16 ch per word, 64 words/row
    float dn = dinv[n];
    uint32_t hu = Hrow[(size_t)n * 64 + lane];
    float acc0 = lo16(hu), acc1 = hi16(hu);
    unsigned int e1 = cursor[n];
    unsigned int e = e1 - (deg[n] - 1u);
    int cnt = (int)(e1 - e);
    for (; cnt >= 4; cnt -= 4, e += 4) {
        int s0 = sorted[e], s1 = sorted[e + 1], s2 = sorted[e + 2], s3 = sorted[e + 3];
        uint32_t u0 = Hrow[(size_t)s0 * 64 + lane];
        uint32_t u1 = Hrow[(size_t)s1 * 64 + lane];
        uint32_t u2 = Hrow[(size_t)s2 * 64 + lane];
        uint32_t u3 = Hrow[(size_t)s3 * 64 + lane];
        acc0 += lo16(u0) + lo16(u1) + lo16(u2) + lo16(u3);
        acc1 += hi16(u0) + hi16(u1) + hi16(u2) + hi16(u3);
    }
    for (; cnt > 0; cnt--, e++) {
        uint32_t u = Hrow[(size_t)sorted[e] * 64 + lane];
        acc0 += lo16(u);
        acc1 += hi16(u);
    }
    float b0, b1v;
    if (flags[0]) { b0 = bf2f(((const bf16_t*)bias)[c0]); b1v = bf2f(((const bf16_t*)bias)[c0 + 1]); }
    else          { b0 = ((const float*)bias)[c0];        b1v = ((const float*)bias)[c0 + 1]; }
    float2 o; o.x = acc0 * dn + b0; o.y = acc1 * dn + b1v;
    *(float2*)(Out + (size_t)n * kHID + c0) = o;
}

__global__ void k_stat1(const float* __restrict__ A1, float* __restrict__ stats) {
    int c = threadIdx.x & 127;
    int r0 = threadIdx.x >> 7;
    int chunk = (kNN + gridDim.x - 1) / gridDim.x;
    int nbeg = blockIdx.x * chunk;
    int nend = nbeg + chunk; if (nend > kNN) nend = kNN;
    float s0 = 0.f, s1 = 0.f;
    for (int n = nbeg + r0; n < nend; n += 2) {
        float v = A1[(size_t)n * kHID + c];
        s0 += v; s1 += v * v;
    }
    atomicAdd(&stats[c], s0);
    atomicAdd(&stats[kHID + c], s1);
}

__global__ void k_bnrelu1(const float* __restrict__ A1, const float* __restrict__ stats,
                          const void* __restrict__ gamma, const void* __restrict__ beta,
                          const int* __restrict__ flags, bf16_t* __restrict__ X1) {
    size_t i = (size_t)blockIdx.x * 256 + threadIdx.x;
    if (i >= (size_t)kNN * kHID) return;
    int c = (int)(i & 127);
    float mu = stats[c] * (1.f / kNN);
    float var = stats[kHID + c] * (1.f / kNN) - mu * mu;
    float g, b;
    if (flags[0]) { g = bf2f(((const bf16_t*)gamma)[c]); b = bf2f(((const bf16_t*)beta)[c]); }
    else          { g = ((const float*)gamma)[c];        b = ((const float*)beta)[c]; }
    float v = (A1[i] - mu) * rsqrtf(var + kEPS) * g + b;
    X1[i] = f2bf(v > 0.f ? v : 0.f);
}

// H2[n,c] = dinv[n] * sum_k X1[n,k]*W2[k,c]  via MFMA (K=128, N=64). X1 always bf16.
__global__ void k_gemm2(const bf16_t* __restrict__ A, const bf16_t* __restrict__ Wz,
                        const float* __restrict__ dinv, bf16_t* __restrict__ H) {
    int wv = threadIdx.x >> 6;
    int l  = threadIdx.x & 63;
    int kgrp = l >> 4;
    int rbase = blockIdx.x * 128 + wv * 32;
    int arow0 = rbase + (l & 15);
    int arow1 = arow0 + 16;
    const short8v* Wv = (const short8v*)Wz;

    f32x4 acc[2][4];
    #pragma unroll
    for (int m = 0; m < 2; m++)
        #pragma unroll
        for (int j = 0; j < 4; j++)
            acc[m][j] = (f32x4){0.f, 0.f, 0.f, 0.f};

    #pragma unroll
    for (int t = 0; t < 4; t++) {
        int kbase = t * 32 + kgrp * 8;
        short8v a0, a1;
        #pragma unroll
        for (int i = 0; i < 8; i++) { a0[i] = 0; a1[i] = 0; }
        if (arow0 < kNN) a0 = *(const short8v*)(A + (size_t)arow0 * kHID + kbase);
        if (arow1 < kNN) a1 = *(const short8v*)(A + (size_t)arow1 * kHID + kbase);
        #pragma unroll
        for (int j = 0; j < 4; j++) {
            short8v b = Wv[(t * 4 + j) * 64 + l];
            acc[0][j] = __builtin_amdgcn_mfma_f32_16x16x32_bf16(a0, b, acc[0][j], 0, 0, 0);
            acc[1][j] = __builtin_amdgcn_mfma_f32_16x16x32_bf16(a1, b, acc[1][j], 0, 0, 0);
        }
    }

    #pragma unroll
    for (int m = 0; m < 2; m++) {
        #pragma unroll
        for (int r = 0; r < 4; r++) {
            int orow = rbase + m * 16 + kgrp * 4 + r;
            if (orow < kNN) {
                float dn = dinv[orow];
                bf16_t* hp = H + (size_t)orow * kOUT + (l & 15);
                #pragma unroll
                for (int j = 0; j < 4; j++) hp[j * 16] = f2bf(acc[m][j][r] * dn);
            }
        }
    }
}

// 8 nodes/block, 32 lanes/node, 2ch/lane, unroll 4
__global__ void k_agg2(const bf16_t* __restrict__ H, const int* __restrict__ sorted,
                       const unsigned int* __restrict__ cursor, const unsigned int* __restrict__ deg,
                       const float* __restrict__ dinv, const void* __restrict__ bias,
                       const int* __restrict__ flags, float* __restrict__ Out) {
    int t = threadIdx.x;
    int local = t >> 5;
    int lane = t & 31;
    int c0 = lane * 2;
    int n = blockIdx.x * 8 + local;
    if (n >= kNN) return;
    const uint32_t* Hrow = (const uint32_t*)H;   // 32 words/row
    float dn = dinv[n];
    uint32_t hu = Hrow[(size_t)n * 32 + lane];
    float acc0 = lo16(hu), acc1 = hi16(hu);
    unsigned int e1 = cursor[n];
    unsigned int e = e1 - (deg[n] - 1u);
    int cnt = (int)(e1 - e);
    for (; cnt >= 4; cnt -= 4, e += 4) {
        int s0 = sorted[e], s1 = sorted[e + 1], s2 = sorted[e + 2], s3 = sorted[e + 3];
        uint32_t u0 = Hrow[(size_t)s0 * 32 + lane];
        uint32_t u1 = Hrow[(size_t)s1 * 32 + lane];
        uint32_t u2 = Hrow[(size_t)s2 * 32 + lane];
        uint32_t u3 = Hrow[(size_t)s3 * 32 + lane];
        acc0 += lo16(u0) + lo16(u1) + lo16(u2) + lo16(u3);
        acc1 += hi16(u0) + hi16(u1) + hi16(u2) + hi16(u3);
    }
    for (; cnt > 0; cnt--, e++) {
        uint32_t u = Hrow[(size_t)sorted[e] * 32 + lane];
        acc0 += lo16(u);
        acc1 += hi16(u);
    }
    float b0, b1v;
    if (flags[0]) { b0 = bf2f(((const bf16_t*)bias)[c0]); b1v = bf2f(((const bf16_t*)bias)[c0 + 1]); }
    else          { b0 = ((const float*)bias)[c0];        b1v = ((const float*)bias)[c0 + 1]; }
    float2 o; o.x = acc0 * dn + b0; o.y = acc1 * dn + b1v;
    *(float2*)(Out + (size_t)n * kOUT + c0) = o;
}

__global__ void k_stat2(const float* __restrict__ A2, float* __restrict__ stats) {
    int c = threadIdx.x & 63;
    int r0 = threadIdx.x >> 6;
    int chunk = (kNN + gridDim.x - 1) / gridDim.x;
    int nbeg = blockIdx.x * chunk;
    int nend = nbeg + chunk; if (nend > kNN) nend = kNN;
    float s0 = 0.f, s1 = 0.f;
    for (int n = nbeg + r0; n < nend; n += 4) {
        float v = A2[(size_t)n * kOUT + c];
        s0 += v; s1 += v * v;
    }
    atomicAdd(&stats[256 + c], s0);
    atomicAdd(&stats[320 + c], s1);
}

__global__ void k_out(const float* __restrict__ A2, const float* __restrict__ stats,
                      const int* __restrict__ batch, const void* __restrict__ gamma,
                      const void* __restrict__ beta, const int* __restrict__ flags,
                      bf16_t* __restrict__ out) {
    int wid = threadIdx.x >> 6;
    int lane = threadIdx.x & 63;
    int i = blockIdx.x * 4 + wid;
    if (i >= kNB) return;
    int n = batch[i];
    int c = lane;
    float mu = stats[256 + c] * (1.f / kNN);
    float var = stats[320 + c] * (1.f / kNN) - mu * mu;
    float g, b;
    if (flags[0]) { g = bf2f(((const bf16_t*)gamma)[c]); b = bf2f(((const bf16_t*)beta)[c]); }
    else          { g = ((const float*)gamma)[c];        b = ((const float*)beta)[c]; }
    float v = (A2[(size_t)n * kOUT + c] - mu) * rsqrtf(var + kEPS) * g + b;
    v = v > 0.f ? v : 0.f;
    float m = v;
    for (int o = 32; o; o >>= 1) m = fmaxf(m, __shfl_xor(m, o));
    float ex = expf(v - m);
    float s = ex;
    for (int o = 32; o; o >>= 1) s += __shfl_xor(s, o);
    float r = v - m - logf(s);
    if (flags[0]) out[(size_t)i * kOUT + c] = f2bf(r);
    else ((float*)out)[(size_t)i * kOUT + c] = r;
}

static inline size_t align_up(size_t x, size_t a) { return (x + a - 1) & ~(a - 1); }

extern "C" void kernel_launch(void* const* d_in, const int* in_sizes, int n_in,
                              void* d_out, int out_size, void* d_ws, size_t ws_size,
                              hipStream_t stream) {
    (void)in_sizes; (void)n_in; (void)out_size; (void)ws_size;
    const void* feat = d_in[0];
    const int* ei    = (const int*)d_in[1];
    const int* batch = (const int*)d_in[2];
    const void* W1   = d_in[3];
    const void* b1   = d_in[4];
    const void* g1   = d_in[5];
    const void* be1  = d_in[6];
    const void* W2   = d_in[7];
    const void* b2   = d_in[8];
    const void* g2   = d_in[9];
    const void* be2  = d_in[10];

    char* ws = (char*)d_ws;
    size_t o = 0;
    int*          flags  = (int*)(ws + o);          o = align_up(o + 32, 256);
    unsigned int* gtotal = (unsigned int*)(ws + o); o = align_up(o + 16, 256);
    unsigned int* deg    = (unsigned int*)(ws + o); o = align_up(o + (size_t)kNN * 4, 256);
    float*        dinv   = (float*)(ws + o);        o = align_up(o + (size_t)kNN * 4, 256);
    unsigned int* cursor = (unsigned int*)(ws + o); o = align_up(o + (size_t)kNN * 4, 256);
    float*        stats  = (float*)(ws + o);        o = align_up(o + 384 * 4, 256);
    int*          sorted = (int*)(ws + o);          o = align_up(o + (size_t)kNE * 4, 256);
    bf16_t*       h1     = (bf16_t*)(ws + o);       o = align_up(o + (size_t)kNN * kHID * 2, 256);
    float*        a1     = (float*)(ws + o);        o = align_up(o + (size_t)kNN * kHID * 4, 256);
    bf16_t*       wz1    = (bf16_t*)(ws + o);       o = align_up(o + (size_t)8 * 8 * 64 * 8 * 2, 256);
    bf16_t*       wz2    = (bf16_t*)(ws + o);       o = align_up(o + (size_t)4 * 4 * 64 * 8 * 2, 256);
    bf16_t*       x1 = h1;                            // h1 dead after agg1
    bf16_t*       h2 = (bf16_t*)a1;                   // a1 dead after bnrelu1
    float*        a2 = (float*)((char*)a1 + 16u * 1024u * 1024u);  // 16MB > 12.8MB h2

    bf16_t* outp = (bf16_t*)d_out;

    // graph build + weight pre-swizzle
    k_probe <<<1, 64, 0, stream>>>((const uint32_t*)feat, (const uint32_t*)ei, flags);
    k_prepw1<<<16, 256, 0, stream>>>(W1, flags, wz1);
    k_prepw2<<<4, 256, 0, stream>>>(W2, flags, wz2);
    k_setup <<<(kNN + 255) / 256, 256, 0, stream>>>(deg, stats, gtotal);
    k_deg   <<<(kNE + 255) / 256, 256, 0, stream>>>(ei, flags, deg);
    k_dinv  <<<(kNN + 255) / 256, 256, 0, stream>>>(deg, dinv);
    k_assign<<<(kNN + 255) / 256, 256, 0, stream>>>(deg, cursor, gtotal);
    k_bucket<<<(kNE + 255) / 256, 256, 0, stream>>>(ei, flags, cursor, sorted);

    // layer 1
    k_gemm1  <<<(kNN + 127) / 128, 256, 0, stream>>>(feat, wz1, dinv, h1, flags);
    k_agg1   <<<(kNN + 3) / 4, 256, 0, stream>>>(h1, sorted, cursor, deg, dinv, b1, flags, a1);
    k_stat1  <<<256, 256, 0, stream>>>(a1, stats);
    k_bnrelu1<<<(kNN * kHID + 255) / 256, 256, 0, stream>>>(a1, stats, g1, be1, flags, x1);

    // layer 2
    k_gemm2<<<(kNN + 127) / 128, 256, 0, stream>>>(x1, wz2, dinv, h2);
    k_agg2 <<<(kNN + 7) / 8, 256, 0, stream>>>(h2, sorted, cursor, deg, dinv, b2, flags, a2);
    k_stat2<<<256, 256, 0, stream>>>(a2, stats);

    // gather + BN2 + relu + log_softmax
    k_out<<<(kNB + 3) / 4, 256, 0, stream>>>(a2, stats, batch, g2, be2, flags, outp);
}

// Round 2
// 533.650 us; speedup vs baseline: 1.4508x; 1.2254x over previous
//
#include <hip/hip_runtime.h>
#include <stdint.h>

typedef unsigned short bf16_t;

constexpr int kNN   = 100000;
constexpr int kNE   = 1600000;
constexpr int kFEAT = 256;
constexpr int kHID  = 128;
constexpr int kOUT  = 64;
constexpr int kNB   = 10000;
constexpr float kEPS = 1e-5f;

constexpr int kEPB  = 4096;                       // edges per hist/scatter block
constexpr int kNBLK = (kNE + kEPB - 1) / kEPB;    // 391
constexpr int kNBUK = (kNN + 511) / 512;          // 196 coarse buckets (512 nodes each)

typedef __attribute__((ext_vector_type(8))) short short8v;
typedef __attribute__((ext_vector_type(4))) float f32x4;

__device__ __forceinline__ float bf2f(bf16_t u) {
    union { uint32_t i; float f; } v; v.i = ((uint32_t)u) << 16; return v.f;
}
__device__ __forceinline__ bf16_t f2bf(float f) {
    uint32_t u = __float_as_uint(f);
    uint32_t r = (u + 0x7FFFu + ((u >> 16) & 1u)) >> 16;
    return (bf16_t)r;
}
__device__ __forceinline__ float lo16(uint32_t u) {
    union { uint32_t i; float f; } v; v.i = u << 16; return v.f;
}
__device__ __forceinline__ float hi16(uint32_t u) {
    union { uint32_t i; float f; } v; v.i = u & 0xFFFF0000u; return v.f;
}

// flags[0]: 1 if float tensors are bf16, 0 if fp32.  flags[1]: 1 if edge_index int64.
__global__ void k_probe(const uint32_t* __restrict__ feat, const uint32_t* __restrict__ ei,
                        int* __restrict__ flags) {
    if (blockIdx.x == 0 && threadIdx.x == 0) {
        int good = 0;
        for (int j = 0; j < 256; j++) {
            uint32_t u = feat[j];
            uint32_t e = (u >> 7) & 0xFFu;
            if (e >= 100u && e <= 132u) good++;
        }
        flags[0] = (good > 128) ? 1 : 0;
        int zeros = 0;
        for (int j = 0; j < 128; j++) {
            if (ei[2 * j + 1] == 0u) zeros++;
        }
        flags[1] = (zeros > 64) ? 1 : 0;
    }
}

// -------- graph build: two-level multisplit (no global atomics) --------

__global__ void k_hist1(const int* __restrict__ ei, const int* __restrict__ flags,
                        unsigned int* __restrict__ counts) {
    __shared__ unsigned int lh[kNBUK];
    int t = threadIdx.x;
    for (int i = t; i < kNBUK; i += 256) lh[i] = 0u;
    __syncthreads();
    int i64 = flags[1];
    int base = blockIdx.x * kEPB;
    for (int k = 0; k < 16; k++) {
        int e = base + k * 256 + t;
        if (e < kNE) {
            int d = i64 ? ei[2 * (kNE + e)] : ei[kNE + e];
            atomicAdd(&lh[d >> 9], 1u);
        }
    }
    __syncthreads();
    for (int i = t; i < kNBUK; i += 256) counts[(size_t)i * kNBLK + blockIdx.x] = lh[i];
}

// bucket totals -> exclusive bases; also zero stats
__global__ void k_scanA(const unsigned int* __restrict__ counts, unsigned int* __restrict__ base,
                        float* __restrict__ stats) {
    __shared__ unsigned int ss[256];
    int t = threadIdx.x;
    for (int i = t; i < 384; i += 256) stats[i] = 0.f;
    unsigned int tot = 0u;
    if (t < kNBUK) {
        const unsigned int* row = counts + (size_t)t * kNBLK;
        for (int j = 0; j < kNBLK; j++) tot += row[j];
    }
    ss[t] = tot;
    __syncthreads();
    for (int o = 1; o < 256; o <<= 1) {
        unsigned int x = (t >= o) ? ss[t - o] : 0u;
        __syncthreads();
        ss[t] += x;
        __syncthreads();
    }
    if (t < kNBUK) base[t] = ss[t] - tot;   // exclusive
    if (t == 0) base[kNBUK] = ss[255];      // == kNE
}

// per-(bucket,block) offsets
__global__ void k_scanB(const unsigned int* __restrict__ counts, const unsigned int* __restrict__ base,
                        unsigned int* __restrict__ off) {
    __shared__ unsigned int ss[64];
    int b = blockIdx.x, t = threadIdx.x;
    unsigned int run = base[b];
    for (int c0 = 0; c0 < kNBLK; c0 += 64) {
        int idx = c0 + t;
        unsigned int v = (idx < kNBLK) ? counts[(size_t)b * kNBLK + idx] : 0u;
        ss[t] = v;
        __syncthreads();
        for (int o = 1; o < 64; o <<= 1) {
            unsigned int x = (t >= o) ? ss[t - o] : 0u;
            __syncthreads();
            ss[t] += x;
            __syncthreads();
        }
        if (idx < kNBLK) off[(size_t)b * kNBLK + idx] = run + ss[t] - v;
        unsigned int ctot = ss[63];
        __syncthreads();
        run += ctot;
    }
}

// coarse scatter: packed (src | dlocal<<17), bucket-grouped runs, LDS cursors only
__global__ void k_scatter1(const int* __restrict__ ei, const int* __restrict__ flags,
                           const unsigned int* __restrict__ off, unsigned int* __restrict__ pairs) {
    __shared__ unsigned int lcur[kNBUK];
    int t = threadIdx.x;
    for (int i = t; i < kNBUK; i += 256) lcur[i] = off[(size_t)i * kNBLK + blockIdx.x];
    __syncthreads();
    int i64 = flags[1];
    int base = blockIdx.x * kEPB;
    for (int k = 0; k < 16; k++) {
        int e = base + k * 256 + t;
        if (e < kNE) {
            int s, d;
            if (i64) { s = ei[2 * e]; d = ei[2 * (kNE + e)]; }
            else     { s = ei[e];     d = ei[kNE + e]; }
            unsigned int p = atomicAdd(&lcur[d >> 9], 1u);
            pairs[p] = (unsigned int)s | ((unsigned int)(d & 511) << 17);
        }
    }
}

// fine scatter: one block per bucket; exact per-node CSR + deg/dinv/cursor
__global__ void __launch_bounds__(1024) k_scatter2(const unsigned int* __restrict__ pairs,
                        const unsigned int* __restrict__ base, unsigned int* __restrict__ deg,
                        float* __restrict__ dinv, unsigned int* __restrict__ cursor,
                        int* __restrict__ sorted) {
    __shared__ unsigned int hist[512], sc[512], lcur[512];
    int b = blockIdx.x, t = threadIdx.x;
    unsigned int gb = base[b];
    int cnt = (int)(base[b + 1] - gb);
    if (t < 512) hist[t] = 0u;
    __syncthreads();
    for (int i = t; i < cnt; i += 1024) atomicAdd(&hist[pairs[gb + i] >> 17], 1u);
    __syncthreads();
    if (t < 512) sc[t] = hist[t];
    __syncthreads();
    for (int o = 1; o < 512; o <<= 1) {
        unsigned int x = 0u;
        if (t < 512 && t >= o) x = sc[t - o];
        __syncthreads();
        if (t < 512) sc[t] += x;
        __syncthreads();
    }
    if (t < 512) {
        lcur[t] = gb + sc[t] - hist[t];
        int node = b * 512 + t;
        if (node < kNN) {
            unsigned int dg = hist[t] + 1u;   // + self loop
            deg[node] = dg;
            dinv[node] = rsqrtf((float)dg);
            cursor[node] = gb + sc[t];        // end of node's slice
        }
    }
    __syncthreads();
    for (int i = t; i < cnt; i += 1024) {
        unsigned int pk = pairs[gb + i];
        unsigned int slot = atomicAdd(&lcur[pk >> 17], 1u);
        sorted[slot] = (int)(pk & 0x1FFFFu);
    }
}

// -------- weights pre-swizzle --------

__global__ void k_prepw1(const void* __restrict__ W, const int* __restrict__ flags,
                         bf16_t* __restrict__ Wz) {
    int idx = blockIdx.x * 256 + threadIdx.x;
    if (idx >= 8 * 8 * 64) return;
    int l = idx & 63;
    int j = (idx >> 6) & 7;
    int t = idx >> 9;
    int col = j * 16 + (l & 15);
    int kb = t * 32 + (l >> 4) * 8;
    bf16_t o[8];
    if (flags[0]) {
        const bf16_t* Wb = (const bf16_t*)W;
        #pragma unroll
        for (int i = 0; i < 8; i++) o[i] = Wb[(size_t)(kb + i) * kHID + col];
    } else {
        const float* Wf = (const float*)W;
        #pragma unroll
        for (int i = 0; i < 8; i++) o[i] = f2bf(Wf[(size_t)(kb + i) * kHID + col]);
    }
    uint4 w;
    w.x = (uint32_t)o[0] | ((uint32_t)o[1] << 16);
    w.y = (uint32_t)o[2] | ((uint32_t)o[3] << 16);
    w.z = (uint32_t)o[4] | ((uint32_t)o[5] << 16);
    w.w = (uint32_t)o[6] | ((uint32_t)o[7] << 16);
    *(uint4*)(Wz + (size_t)idx * 8) = w;
}

__global__ void k_prepw2(const void* __restrict__ W, const int* __restrict__ flags,
                         bf16_t* __restrict__ Wz) {
    int idx = blockIdx.x * 256 + threadIdx.x;
    if (idx >= 4 * 4 * 64) return;
    int l = idx & 63;
    int j = (idx >> 6) & 3;
    int t = idx >> 8;
    int col = j * 16 + (l & 15);
    int kb = t * 32 + (l >> 4) * 8;
    bf16_t o[8];
    if (flags[0]) {
        const bf16_t* Wb = (const bf16_t*)W;
        #pragma unroll
        for (int i = 0; i < 8; i++) o[i] = Wb[(size_t)(kb + i) * kOUT + col];
    } else {
        const float* Wf = (const float*)W;
        #pragma unroll
        for (int i = 0; i < 8; i++) o[i] = f2bf(Wf[(size_t)(kb + i) * kOUT + col]);
    }
    uint4 w;
    w.x = (uint32_t)o[0] | ((uint32_t)o[1] << 16);
    w.y = (uint32_t)o[2] | ((uint32_t)o[3] << 16);
    w.z = (uint32_t)o[4] | ((uint32_t)o[5] << 16);
    w.w = (uint32_t)o[6] | ((uint32_t)o[7] << 16);
    *(uint4*)(Wz + (size_t)idx * 8) = w;
}

// -------- layer 1 GEMM (MFMA) --------
__global__ void k_gemm1(const void* __restrict__ A, const bf16_t* __restrict__ Wz,
                        const float* __restrict__ dinv, bf16_t* __restrict__ H,
                        const int* __restrict__ flags) {
    int isbf = flags[0];
    int wv = threadIdx.x >> 6;
    int l  = threadIdx.x & 63;
    int kgrp = l >> 4;
    int rbase = blockIdx.x * 128 + wv * 32;
    int arow0 = rbase + (l & 15);
    int arow1 = arow0 + 16;
    const bf16_t* Ab = (const bf16_t*)A;
    const float*  Af = (const float*)A;
    const short8v* Wv = (const short8v*)Wz;

    f32x4 acc[2][8];
    #pragma unroll
    for (int m = 0; m < 2; m++)
        #pragma unroll
        for (int j = 0; j < 8; j++)
            acc[m][j] = (f32x4){0.f, 0.f, 0.f, 0.f};

    #pragma unroll
    for (int t = 0; t < 8; t++) {
        int kbase = t * 32 + kgrp * 8;
        short8v a0, a1;
        #pragma unroll
        for (int i = 0; i < 8; i++) { a0[i] = 0; a1[i] = 0; }
        if (arow0 < kNN) {
            if (isbf) {
                a0 = *(const short8v*)(Ab + (size_t)arow0 * kFEAT + kbase);
            } else {
                const float* p = Af + (size_t)arow0 * kFEAT + kbase;
                #pragma unroll
                for (int i = 0; i < 8; i++) a0[i] = (short)f2bf(p[i]);
            }
        }
        if (arow1 < kNN) {
            if (isbf) {
                a1 = *(const short8v*)(Ab + (size_t)arow1 * kFEAT + kbase);
            } else {
                const float* p = Af + (size_t)arow1 * kFEAT + kbase;
                #pragma unroll
                for (int i = 0; i < 8; i++) a1[i] = (short)f2bf(p[i]);
            }
        }
        #pragma unroll
        for (int j = 0; j < 8; j++) {
            short8v b = Wv[(t * 8 + j) * 64 + l];
            acc[0][j] = __builtin_amdgcn_mfma_f32_16x16x32_bf16(a0, b, acc[0][j], 0, 0, 0);
            acc[1][j] = __builtin_amdgcn_mfma_f32_16x16x32_bf16(a1, b, acc[1][j], 0, 0, 0);
        }
    }

    #pragma unroll
    for (int m = 0; m < 2; m++) {
        #pragma unroll
        for (int r = 0; r < 4; r++) {
            int orow = rbase + m * 16 + kgrp * 4 + r;
            if (orow < kNN) {
                float dn = dinv[orow];
                bf16_t* hp = H + (size_t)orow * kHID + (l & 15);
                #pragma unroll
                for (int j = 0; j < 8; j++) hp[j * 16] = f2bf(acc[m][j][r] * dn);
            }
        }
    }
}

// A1[n,c] = dinv[n]*(sum_edges Hs[s,c] + Hs[n,c]) + b1[c]
__global__ void k_agg1(const bf16_t* __restrict__ H, const int* __restrict__ sorted,
                       const unsigned int* __restrict__ cursor, const unsigned int* __restrict__ deg,
                       const float* __restrict__ dinv, const void* __restrict__ bias,
                       const int* __restrict__ flags, float* __restrict__ Out) {
    int t = threadIdx.x;
    int local = t >> 6;
    int lane = t & 63;
    int c0 = lane * 2;
    int n = blockIdx.x * 4 + local;
    if (n >= kNN) return;
    const uint32_t* Hrow = (const uint32_t*)H;   // 2 bf16 ch per word, 64 words/row
    float dn = dinv[n];
    uint32_t hu = Hrow[(size_t)n * 64 + lane];
    float acc0 = lo16(hu), acc1 = hi16(hu);
    unsigned int e1 = cursor[n];
    unsigned int e = e1 - (deg[n] - 1u);
    int cnt = (int)(e1 - e);
    for (; cnt >= 4; cnt -= 4, e += 4) {
        int s0 = sorted[e], s1 = sorted[e + 1], s2 = sorted[e + 2], s3 = sorted[e + 3];
        uint32_t u0 = Hrow[(size_t)s0 * 64 + lane];
        uint32_t u1 = Hrow[(size_t)s1 * 64 + lane];
        uint32_t u2 = Hrow[(size_t)s2 * 64 + lane];
        uint32_t u3 = Hrow[(size_t)s3 * 64 + lane];
        acc0 += lo16(u0) + lo16(u1) + lo16(u2) + lo16(u3);
        acc1 += hi16(u0) + hi16(u1) + hi16(u2) + hi16(u3);
    }
    for (; cnt > 0; cnt--, e++) {
        uint32_t u = Hrow[(size_t)sorted[e] * 64 + lane];
        acc0 += lo16(u);
        acc1 += hi16(u);
    }
    float b0, b1v;
    if (flags[0]) { b0 = bf2f(((const bf16_t*)bias)[c0]); b1v = bf2f(((const bf16_t*)bias)[c0 + 1]); }
    else          { b0 = ((const float*)bias)[c0];        b1v = ((const float*)bias)[c0 + 1]; }
    float2 o; o.x = acc0 * dn + b0; o.y = acc1 * dn + b1v;
    *(float2*)(Out + (size_t)n * kHID + c0) = o;
}

__global__ void k_stat1(const float* __restrict__ A1, float* __restrict__ stats) {
    int c = threadIdx.x & 127;
    int r0 = threadIdx.x >> 7;
    int chunk = (kNN + gridDim.x - 1) / gridDim.x;
    int nbeg = blockIdx.x * chunk;
    int nend = nbeg + chunk; if (nend > kNN) nend = kNN;
    float s0 = 0.f, s1 = 0.f;
    for (int n = nbeg + r0; n < nend; n += 2) {
        float v = A1[(size_t)n * kHID + c];
        s0 += v; s1 += v * v;
    }
    atomicAdd(&stats[c], s0);
    atomicAdd(&stats[kHID + c], s1);
}

__global__ void k_bnrelu1(const float* __restrict__ A1, const float* __restrict__ stats,
                          const void* __restrict__ gamma, const void* __restrict__ beta,
                          const int* __restrict__ flags, bf16_t* __restrict__ X1) {
    size_t i = (size_t)blockIdx.x * 256 + threadIdx.x;
    if (i >= (size_t)kNN * kHID) return;
    int c = (int)(i & 127);
    float mu = stats[c] * (1.f / kNN);
    float var = stats[kHID + c] * (1.f / kNN) - mu * mu;
    float g, b;
    if (flags[0]) { g = bf2f(((const bf16_t*)gamma)[c]); b = bf2f(((const bf16_t*)beta)[c]); }
    else          { g = ((const float*)gamma)[c];        b = ((const float*)beta)[c]; }
    float v = (A1[i] - mu) * rsqrtf(var + kEPS) * g + b;
    X1[i] = f2bf(v > 0.f ? v : 0.f);
}

// -------- layer 2 GEMM (MFMA), X1 always bf16 --------
__global__ void k_gemm2(const bf16_t* __restrict__ A, const bf16_t* __restrict__ Wz,
                        const float* __restrict__ dinv, bf16_t* __restrict__ H) {
    int wv = threadIdx.x >> 6;
    int l  = threadIdx.x & 63;
    int kgrp = l >> 4;
    int rbase = blockIdx.x * 128 + wv * 32;
    int arow0 = rbase + (l & 15);
    int arow1 = arow0 + 16;
    const short8v* Wv = (const short8v*)Wz;

    f32x4 acc[2][4];
    #pragma unroll
    for (int m = 0; m < 2; m++)
        #pragma unroll
        for (int j = 0; j < 4; j++)
            acc[m][j] = (f32x4){0.f, 0.f, 0.f, 0.f};

    #pragma unroll
    for (int t = 0; t < 4; t++) {
        int kbase = t * 32 + kgrp * 8;
        short8v a0, a1;
        #pragma unroll
        for (int i = 0; i < 8; i++) { a0[i] = 0; a1[i] = 0; }
        if (arow0 < kNN) a0 = *(const short8v*)(A + (size_t)arow0 * kHID + kbase);
        if (arow1 < kNN) a1 = *(const short8v*)(A + (size_t)arow1 * kHID + kbase);
        #pragma unroll
        for (int j = 0; j < 4; j++) {
            short8v b = Wv[(t * 4 + j) * 64 + l];
            acc[0][j] = __builtin_amdgcn_mfma_f32_16x16x32_bf16(a0, b, acc[0][j], 0, 0, 0);
            acc[1][j] = __builtin_amdgcn_mfma_f32_16x16x32_bf16(a1, b, acc[1][j], 0, 0, 0);
        }
    }

    #pragma unroll
    for (int m = 0; m < 2; m++) {
        #pragma unroll
        for (int r = 0; r < 4; r++) {
            int orow = rbase + m * 16 + kgrp * 4 + r;
            if (orow < kNN) {
                float dn = dinv[orow];
                bf16_t* hp = H + (size_t)orow * kOUT + (l & 15);
                #pragma unroll
                for (int j = 0; j < 4; j++) hp[j * 16] = f2bf(acc[m][j][r] * dn);
            }
        }
    }
}

__global__ void k_agg2(const bf16_t* __restrict__ H, const int* __restrict__ sorted,
                       const unsigned int* __restrict__ cursor, const unsigned int* __restrict__ deg,
                       const float* __restrict__ dinv, const void* __restrict__ bias,
                       const int* __restrict__ flags, float* __restrict__ Out) {
    int t = threadIdx.x;
    int local = t >> 5;
    int lane = t & 31;
    int c0 = lane * 2;
    int n = blockIdx.x * 8 + local;
    if (n >= kNN) return;
    const uint32_t* Hrow = (const uint32_t*)H;   // 32 words/row
    float dn = dinv[n];
    uint32_t hu = Hrow[(size_t)n * 32 + lane];
    float acc0 = lo16(hu), acc1 = hi16(hu);
    unsigned int e1 = cursor[n];
    unsigned int e = e1 - (deg[n] - 1u);
    int cnt = (int)(e1 - e);
    for (; cnt >= 4; cnt -= 4, e += 4) {
        int s0 = sorted[e], s1 = sorted[e + 1], s2 = sorted[e + 2], s3 = sorted[e + 3];
        uint32_t u0 = Hrow[(size_t)s0 * 32 + lane];
        uint32_t u1 = Hrow[(size_t)s1 * 32 + lane];
        uint32_t u2 = Hrow[(size_t)s2 * 32 + lane];
        uint32_t u3 = Hrow[(size_t)s3 * 32 + lane];
        acc0 += lo16(u0) + lo16(u1) + lo16(u2) + lo16(u3);
        acc1 += hi16(u0) + hi16(u1) + hi16(u2) + hi16(u3);
    }
    for (; cnt > 0; cnt--, e++) {
        uint32_t u = Hrow[(size_t)sorted[e] * 32 + lane];
        acc0 += lo16(u);
        acc1 += hi16(u);
    }
    float b0, b1v;
    if (flags[0]) { b0 = bf2f(((const bf16_t*)bias)[c0]); b1v = bf2f(((const bf16_t*)bias)[c0 + 1]); }
    else          { b0 = ((const float*)bias)[c0];        b1v = ((const float*)bias)[c0 + 1]; }
    float2 o; o.x = acc0 * dn + b0; o.y = acc1 * dn + b1v;
    *(float2*)(Out + (size_t)n * kOUT + c0) = o;
}

__global__ void k_stat2(const float* __restrict__ A2, float* __restrict__ stats) {
    int c = threadIdx.x & 63;
    int r0 = threadIdx.x >> 6;
    int chunk = (kNN + gridDim.x - 1) / gridDim.x;
    int nbeg = blockIdx.x * chunk;
    int nend = nbeg + chunk; if (nend > kNN) nend = kNN;
    float s0 = 0.f, s1 = 0.f;
    for (int n = nbeg + r0; n < nend; n += 4) {
        float v = A2[(size_t)n * kOUT + c];
        s0 += v; s1 += v * v;
    }
    atomicAdd(&stats[256 + c], s0);
    atomicAdd(&stats[320 + c], s1);
}

__global__ void k_out(const float* __restrict__ A2, const float* __restrict__ stats,
                      const int* __restrict__ batch, const void* __restrict__ gamma,
                      const void* __restrict__ beta, const int* __restrict__ flags,
                      bf16_t* __restrict__ out) {
    int wid = threadIdx.x >> 6;
    int lane = threadIdx.x & 63;
    int i = blockIdx.x * 4 + wid;
    if (i >= kNB) return;
    int n = batch[i];
    int c = lane;
    float mu = stats[256 + c] * (1.f / kNN);
    float var = stats[320 + c] * (1.f / kNN) - mu * mu;
    float g, b;
    if (flags[0]) { g = bf2f(((const bf16_t*)gamma)[c]); b = bf2f(((const bf16_t*)beta)[c]); }
    else          { g = ((const float*)gamma)[c];        b = ((const float*)beta)[c]; }
    float v = (A2[(size_t)n * kOUT + c] - mu) * rsqrtf(var + kEPS) * g + b;
    v = v > 0.f ? v : 0.f;
    float m = v;
    for (int o = 32; o; o >>= 1) m = fmaxf(m, __shfl_xor(m, o));
    float ex = expf(v - m);
    float s = ex;
    for (int o = 32; o; o >>= 1) s += __shfl_xor(s, o);
    float r = v - m - logf(s);
    if (flags[0]) out[(size_t)i * kOUT + c] = f2bf(r);
    else ((float*)out)[(size_t)i * kOUT + c] = r;
}

static inline size_t align_up(size_t x, size_t a) { return (x + a - 1) & ~(a - 1); }

extern "C" void kernel_launch(void* const* d_in, const int* in_sizes, int n_in,
                              void* d_out, int out_size, void* d_ws, size_t ws_size,
                              hipStream_t stream) {
    (void)in_sizes; (void)n_in; (void)out_size; (void)ws_size;
    const void* feat = d_in[0];
    const int* ei    = (const int*)d_in[1];
    const int* batch = (const int*)d_in[2];
    const void* W1   = d_in[3];
    const void* b1   = d_in[4];
    const void* g1   = d_in[5];
    const void* be1  = d_in[6];
    const void* W2   = d_in[7];
    const void* b2   = d_in[8];
    const void* g2   = d_in[9];
    const void* be2  = d_in[10];

    char* ws = (char*)d_ws;
    size_t o = 0;
    int*          flags  = (int*)(ws + o);          o = align_up(o + 32, 256);
    unsigned int* deg    = (unsigned int*)(ws + o); o = align_up(o + (size_t)kNN * 4, 256);
    float*        dinv   = (float*)(ws + o);        o = align_up(o + (size_t)kNN * 4, 256);
    unsigned int* cursor = (unsigned int*)(ws + o); o = align_up(o + (size_t)kNN * 4, 256);
    float*        stats  = (float*)(ws + o);        o = align_up(o + 384 * 4, 256);
    int*          sorted = (int*)(ws + o);          o = align_up(o + (size_t)kNE * 4, 256);
    bf16_t*       h1     = (bf16_t*)(ws + o);       o = align_up(o + (size_t)kNN * kHID * 2, 256);
    float*        a1     = (float*)(ws + o);        o = align_up(o + (size_t)kNN * kHID * 4, 256);
    bf16_t*       wz1    = (bf16_t*)(ws + o);       o = align_up(o + (size_t)8 * 8 * 64 * 8 * 2, 256);
    bf16_t*       wz2    = (bf16_t*)(ws + o);       o = align_up(o + (size_t)4 * 4 * 64 * 8 * 2, 256);

    // build-phase aliases (dead by the time their hosts are written, stream-ordered):
    unsigned int* pairs  = (unsigned int*)h1;                    // 6.4MB < 25.6MB
    unsigned int* counts = (unsigned int*)a1;                    // 306KB
    unsigned int* offm   = (unsigned int*)((char*)a1 + 512 * 1024);   // 306KB
    unsigned int* gbase  = (unsigned int*)((char*)a1 + 1024 * 1024);  // 788B

    bf16_t*       x1 = h1;                            // h1 dead after agg1
    bf16_t*       h2 = (bf16_t*)a1;                   // a1 dead after bnrelu1
    float*        a2 = (float*)((char*)a1 + 16u * 1024u * 1024u);  // 16MB > 12.8MB h2

    bf16_t* outp = (bf16_t*)d_out;

    // graph build (two-level multisplit) + weight pre-swizzle
    k_probe   <<<1, 64, 0, stream>>>((const uint32_t*)feat, (const uint32_t*)ei, flags);
    k_prepw1  <<<16, 256, 0, stream>>>(W1, flags, wz1);
    k_prepw2  <<<4, 256, 0, stream>>>(W2, flags, wz2);
    k_hist1   <<<kNBLK, 256, 0, stream>>>(ei, flags, counts);
    k_scanA   <<<1, 256, 0, stream>>>(counts, gbase, stats);
    k_scanB   <<<kNBUK, 64, 0, stream>>>(counts, gbase, offm);
    k_scatter1<<<kNBLK, 256, 0, stream>>>(ei, flags, offm, pairs);
    k_scatter2<<<kNBUK, 1024, 0, stream>>>(pairs, gbase, deg, dinv, cursor, sorted);

    // layer 1
    k_gemm1  <<<(kNN + 127) / 128, 256, 0, stream>>>(feat, wz1, dinv, h1, flags);
    k_agg1   <<<(kNN + 3) / 4, 256, 0, stream>>>(h1, sorted, cursor, deg, dinv, b1, flags, a1);
    k_stat1  <<<256, 256, 0, stream>>>(a1, stats);
    k_bnrelu1<<<(kNN * kHID + 255) / 256, 256, 0, stream>>>(a1, stats, g1, be1, flags, x1);

    // layer 2
    k_gemm2<<<(kNN + 127) / 128, 256, 0, stream>>>(x1, wz2, dinv, h2);
    k_agg2 <<<(kNN + 7) / 8, 256, 0, stream>>>(h2, sorted, cursor, deg, dinv, b2, flags, a2);
    k_stat2<<<256, 256, 0, stream>>>(a2, stats);

    // gather + BN2 + relu + log_softmax
    k_out<<<(kNB + 3) / 4, 256, 0, stream>>>(a2, stats, batch, g2, be2, flags, outp);
}